// Round 8
// baseline (95440.192 us; speedup 1.0000x reference)
//
#include <hip/hip_runtime.h>
#include <hip/hip_bf16.h>
#include <hip/hip_fp16.h>

#define HN 256
#define DN 128
#define SL 1024
#define BN 128
#define NUNF 6

static __device__ __forceinline__ float fexp2(float x) { return __builtin_amdgcn_exp2f(x); }
static __device__ __forceinline__ float frcp(float x) { return __builtin_amdgcn_rcpf(x); }

// Packed param element (8 B): .x = bits of half2{A, Bc}, .y = Ws (f32)
//   recurrent (i,h): A = -sigma*log2e, Bc = sigma*mu*log2e, Ws = softplus(w)*erev
//   sensory   (d,h): A = -ssig*log2e*iw[d], Bc = ssig*(smu-ib[d])*log2e, Ws = softplus(sw)*serev
// Layout transposed: rp2[h*HN + i], spp2[h*DN + d]  (per-thread contiguous)
__global__ void ltc_prep(const float* __restrict__ gleak, const float* __restrict__ vleak,
                         const float* __restrict__ cm,    const float* __restrict__ w,
                         const float* __restrict__ sigma, const float* __restrict__ mu,
                         const float* __restrict__ erev,
                         const float* __restrict__ sw,    const float* __restrict__ ssig,
                         const float* __restrict__ smu,   const float* __restrict__ serev,
                         const float* __restrict__ iw,    const float* __restrict__ ib,
                         float* __restrict__ ws)
{
    const float L2E = 1.44269504088896340736f;
    float2* rp2  = (float2*)ws;                        // 65536 float2 (512 KB)
    float2* spp2 = (float2*)ws + HN * HN;              // 32768 float2 (256 KB)
    float*  hv   = ws + 2 * (HN * HN + DN * HN);       // 768 floats
    const int stride = gridDim.x * blockDim.x;
    const int tid0 = blockIdx.x * blockDim.x + threadIdx.x;

    for (int idx = tid0; idx < HN * HN; idx += stride) {
        int i = idx >> 8, h = idx & (HN - 1);
        float sg = sigma[idx];
        float wp = log1pf(expf(w[idx]));        // softplus
        unsigned int ua = __half_as_ushort(__float2half_rn(-sg * L2E));
        unsigned int ub = __half_as_ushort(__float2half_rn(sg * mu[idx] * L2E));
        float2 e;
        e.x = __uint_as_float(ua | (ub << 16));
        e.y = wp * erev[idx];                   // erev is exactly +/-1
        rp2[h * HN + i] = e;
    }
    for (int idx = tid0; idx < DN * HN; idx += stride) {
        int d = idx >> 8, h = idx & (HN - 1);
        float sg = ssig[idx];
        float wp = log1pf(expf(sw[idx]));
        unsigned int ua = __half_as_ushort(__float2half_rn(-sg * L2E * iw[d]));
        unsigned int ub = __half_as_ushort(__float2half_rn(sg * (smu[idx] - ib[d]) * L2E));
        float2 e;
        e.x = __uint_as_float(ua | (ub << 16));
        e.y = wp * serev[idx];
        spp2[h * DN + d] = e;
    }
    if (tid0 < HN) {
        float gl = log1pf(expf(gleak[tid0]));
        float ct = log1pf(expf(cm[tid0])) * (float)NUNF;
        hv[tid0]          = gl * vleak[tid0];
        hv[HN + tid0]     = ct;
        hv[2 * HN + tid0] = ct + gl;
    }
}

// one packed element -> accumulate sigmoid into nm/dn
static __device__ __forceinline__ void sig_acc(float px, float py, float v,
                                               float& nm, float& dn) {
    __half2 h2 = *reinterpret_cast<const __half2*>(&px);
    float A = __low2float(h2);
    float B = __high2float(h2);
    float e = fexp2(fmaf(A, v, B));
    float r = frcp(1.0f + e);
    nm = fmaf(py, r, nm);
    dn = fmaf(fabsf(py), r, dn);
}

// One block per batch element. 1024 threads: h = tid&255 (output column),
// c = tid>>8 (reduction chunk over i or d).
__global__ __launch_bounds__(1024) void ltc_main(
    const float* __restrict__ x, const float2* __restrict__ rp2,
    const float2* __restrict__ spp2, const float* __restrict__ hv,
    float* __restrict__ out)
{
    const int b = blockIdx.x;
    const int tid = threadIdx.x;
    const int h = tid & (HN - 1);
    const int c = tid >> 8;

    __shared__ __align__(16) float v_[HN];
    __shared__ __align__(16) float xs[DN];
    __shared__ __align__(16) float sred[4][HN][2];
    __shared__ __align__(16) float sredS[4][HN][2];

    float cmt = 0.f, gv = 0.f, dcn = 0.f;
    if (tid < HN) {
        gv  = hv[tid];
        cmt = hv[HN + tid];
        dcn = hv[2 * HN + tid];
        v_[tid] = 0.f;
    }
    __syncthreads();

    // per-thread contiguous param slices
    const float4* rpv = reinterpret_cast<const float4*>(rp2 + (size_t)h * HN + c * 64);   // 32 float4
    const float4* spv = reinterpret_cast<const float4*>(spp2 + (size_t)h * DN + c * 32);  // 16 float4

    const float* xrow = x + (size_t)b * SL * DN;
    float* orow = out + (size_t)b * SL * HN;
    float wns = 0.f, wds = 0.f, vnew = 0.f;

    for (int t = 0; t < SL; ++t) {
        if (tid < DN) xs[tid] = xrow[(size_t)t * DN + tid];
        __syncthreads();

        // ---- sensory stage: 32 elements per thread ----
        {
            float sn = 0.f, sd = 0.f;
            const float4* xv4 = reinterpret_cast<const float4*>(&xs[c * 32]);
            #pragma unroll 2
            for (int jj = 0; jj < 4; ++jj) {
                float4 P0 = spv[4 * jj + 0], P1 = spv[4 * jj + 1];
                float4 P2 = spv[4 * jj + 2], P3 = spv[4 * jj + 3];
                float4 va = xv4[2 * jj], vb = xv4[2 * jj + 1];
                sig_acc(P0.x, P0.y, va.x, sn, sd);
                sig_acc(P0.z, P0.w, va.y, sn, sd);
                sig_acc(P1.x, P1.y, va.z, sn, sd);
                sig_acc(P1.z, P1.w, va.w, sn, sd);
                sig_acc(P2.x, P2.y, vb.x, sn, sd);
                sig_acc(P2.z, P2.w, vb.y, sn, sd);
                sig_acc(P3.x, P3.y, vb.z, sn, sd);
                sig_acc(P3.z, P3.w, vb.w, sn, sd);
            }
            sredS[c][h][0] = sn;
            sredS[c][h][1] = sd;
        }
        __syncthreads();
        if (tid < HN) {
            wns = sredS[0][tid][0] + sredS[1][tid][0] + sredS[2][tid][0] + sredS[3][tid][0];
            wds = sredS[0][tid][1] + sredS[1][tid][1] + sredS[2][tid][1] + sredS[3][tid][1];
        }

        // ---- 6 ODE unfolds: 64 elements per thread ----
        #pragma unroll 1
        for (int k = 0; k < NUNF; ++k) {
            float nm = 0.f, dn = 0.f;
            const float4* v4 = reinterpret_cast<const float4*>(&v_[c * 64]);
            #pragma unroll 2
            for (int jj = 0; jj < 8; ++jj) {
                float4 P0 = rpv[4 * jj + 0], P1 = rpv[4 * jj + 1];
                float4 P2 = rpv[4 * jj + 2], P3 = rpv[4 * jj + 3];
                float4 va = v4[2 * jj], vb = v4[2 * jj + 1];
                sig_acc(P0.x, P0.y, va.x, nm, dn);
                sig_acc(P0.z, P0.w, va.y, nm, dn);
                sig_acc(P1.x, P1.y, va.z, nm, dn);
                sig_acc(P1.z, P1.w, va.w, nm, dn);
                sig_acc(P2.x, P2.y, vb.x, nm, dn);
                sig_acc(P2.z, P2.w, vb.y, nm, dn);
                sig_acc(P3.x, P3.y, vb.z, nm, dn);
                sig_acc(P3.z, P3.w, vb.w, nm, dn);
            }
            sred[c][h][0] = nm;
            sred[c][h][1] = dn;
            __syncthreads();
            if (tid < HN) {
                float num = sred[0][tid][0] + sred[1][tid][0] + sred[2][tid][0] + sred[3][tid][0] + wns;
                float den = sred[0][tid][1] + sred[1][tid][1] + sred[2][tid][1] + sred[3][tid][1] + wds;
                float vo = v_[tid];
                num = fmaf(cmt, vo, gv) + num;
                den = dcn + den + 1e-8f;
                vnew = num * frcp(den);
                v_[tid] = vnew;
            }
            __syncthreads();
        }

        if (tid < HN) orow[(size_t)t * HN + tid] = vnew;
    }
    if (tid < HN) out[(size_t)BN * SL * HN + (size_t)b * HN + tid] = vnew;
}

extern "C" void kernel_launch(void* const* d_in, const int* in_sizes, int n_in,
                              void* d_out, int out_size, void* d_ws, size_t ws_size,
                              hipStream_t stream) {
    const float* x     = (const float*)d_in[0];
    const float* gleak = (const float*)d_in[1];
    const float* vleak = (const float*)d_in[2];
    const float* cm    = (const float*)d_in[3];
    const float* w     = (const float*)d_in[4];
    const float* sigma = (const float*)d_in[5];
    const float* mu    = (const float*)d_in[6];
    const float* erev  = (const float*)d_in[7];
    const float* sw    = (const float*)d_in[8];
    const float* ssig  = (const float*)d_in[9];
    const float* smu   = (const float*)d_in[10];
    const float* serev = (const float*)d_in[11];
    const float* iw    = (const float*)d_in[12];
    const float* ib    = (const float*)d_in[13];

    float* ws = (float*)d_ws;

    ltc_prep<<<128, 256, 0, stream>>>(gleak, vleak, cm, w, sigma, mu, erev,
                                      sw, ssig, smu, serev, iw, ib, ws);

    const float2* rp2  = (const float2*)ws;
    const float2* spp2 = (const float2*)ws + HN * HN;
    const float*  hv   = ws + 2 * (HN * HN + DN * HN);
    ltc_main<<<BN, 1024, 0, stream>>>(x, rp2, spp2, hv, (float*)d_out);
}

// Round 11
// 59247.955 us; speedup vs baseline: 1.6109x; 1.6109x over previous
//
#include <hip/hip_runtime.h>
#include <hip/hip_bf16.h>
#include <hip/hip_fp16.h>

#define HN 256
#define DN 128
#define SL 1024
#define BN 128
#define NUNF 6

static __device__ __forceinline__ float fexp2(float x) { return __builtin_amdgcn_exp2f(x); }
static __device__ __forceinline__ float frcp(float x) { return __builtin_amdgcn_rcpf(x); }

// Packed param element (8 B): .x = bits of half2{A, Bc}, .y = Ws (f32)
//   recurrent (i,h): A = -sigma*log2e, Bc = sigma*mu*log2e, Ws = softplus(w)*erev
//   sensory   (d,h): A = -ssig*log2e*iw[d], Bc = ssig*(smu-ib[d])*log2e, Ws = softplus(sw)*serev
// Layout NATURAL [i][h] (i-major): rp2[i*HN + h] — lane-coalesced across h
// (64 consecutive lanes read 64 consecutive float2 = 512 B/instruction).
__global__ void ltc_prep(const float* __restrict__ gleak, const float* __restrict__ vleak,
                         const float* __restrict__ cm,    const float* __restrict__ w,
                         const float* __restrict__ sigma, const float* __restrict__ mu,
                         const float* __restrict__ erev,
                         const float* __restrict__ sw,    const float* __restrict__ ssig,
                         const float* __restrict__ smu,   const float* __restrict__ serev,
                         const float* __restrict__ iw,    const float* __restrict__ ib,
                         float* __restrict__ ws)
{
    const float L2E = 1.44269504088896340736f;
    float2* rp2  = (float2*)ws;                        // 65536 float2 (512 KB)
    float2* spp2 = (float2*)ws + HN * HN;              // 32768 float2 (256 KB)
    float*  hv   = ws + 2 * (HN * HN + DN * HN);       // 768 floats
    const int stride = gridDim.x * blockDim.x;
    const int tid0 = blockIdx.x * blockDim.x + threadIdx.x;

    for (int idx = tid0; idx < HN * HN; idx += stride) {
        float sg = sigma[idx];
        float wp = log1pf(expf(w[idx]));        // softplus
        unsigned int ua = __half_as_ushort(__float2half_rn(-sg * L2E));
        unsigned int ub = __half_as_ushort(__float2half_rn(sg * mu[idx] * L2E));
        float2 e;
        e.x = __uint_as_float(ua | (ub << 16));
        e.y = wp * erev[idx];                   // erev is exactly +/-1
        rp2[idx] = e;                           // idx = i*HN + h (natural order)
    }
    for (int idx = tid0; idx < DN * HN; idx += stride) {
        int d = idx >> 8;                       // idx = d*HN + h
        float sg = ssig[idx];
        float wp = log1pf(expf(sw[idx]));
        unsigned int ua = __half_as_ushort(__float2half_rn(-sg * L2E * iw[d]));
        unsigned int ub = __half_as_ushort(__float2half_rn(sg * (smu[idx] - ib[d]) * L2E));
        float2 e;
        e.x = __uint_as_float(ua | (ub << 16));
        e.y = wp * serev[idx];
        spp2[idx] = e;
    }
    if (tid0 < HN) {
        float gl = log1pf(expf(gleak[tid0]));
        float ct = log1pf(expf(cm[tid0])) * (float)NUNF;
        hv[tid0]          = gl * vleak[tid0];
        hv[HN + tid0]     = ct;
        hv[2 * HN + tid0] = ct + gl;
    }
}

// one packed element -> accumulate sigmoid into nm/dn
static __device__ __forceinline__ void sig_acc(float2 p, float v,
                                               float& nm, float& dn) {
    __half2 h2 = *reinterpret_cast<const __half2*>(&p.x);
    float A = __low2float(h2);
    float B = __high2float(h2);
    float e = fexp2(fmaf(A, v, B));
    float r = frcp(1.0f + e);
    nm = fmaf(p.y, r, nm);
    dn = fmaf(fabsf(p.y), r, dn);
}

// One block per batch element. 1024 threads: h = tid&255 (output column),
// c = tid>>8 (reduction chunk over i or d). Param loads are float2 at
// [(chunk_i + j)*HN + h]: lane-coalesced, one dwordx2 per element,
// batched 8-deep for MLP.
__global__ __launch_bounds__(1024) void ltc_main(
    const float* __restrict__ x, const float2* __restrict__ rp2,
    const float2* __restrict__ spp2, const float* __restrict__ hv,
    float* __restrict__ out)
{
    const int b = blockIdx.x;
    const int tid = threadIdx.x;
    const int h = tid & (HN - 1);
    const int c = tid >> 8;

    __shared__ __align__(16) float v_[HN];
    __shared__ __align__(16) float xs[DN];
    __shared__ __align__(16) float sred[4][HN][2];
    __shared__ __align__(16) float sredS[4][HN][2];

    float cmt = 0.f, gv = 0.f, dcn = 0.f;
    if (tid < HN) {
        gv  = hv[tid];
        cmt = hv[HN + tid];
        dcn = hv[2 * HN + tid];
        v_[tid] = 0.f;
    }
    __syncthreads();

    // per-thread param columns (lane-coalesced across h)
    const float2* __restrict__ prow = rp2  + (size_t)(c * 64) * HN + h;  // elem j at prow[j*HN]
    const float2* __restrict__ srow = spp2 + (size_t)(c * 32) * HN + h;

    const float* xrow = x + (size_t)b * SL * DN;
    float* orow = out + (size_t)b * SL * HN;
    float wns = 0.f, wds = 0.f, vnew = 0.f;

    for (int t = 0; t < SL; ++t) {
        if (tid < DN) xs[tid] = xrow[(size_t)t * DN + tid];
        __syncthreads();

        // ---- sensory stage: 32 elements per thread ----
        {
            float sn = 0.f, sd = 0.f;
            const float4* xv4 = reinterpret_cast<const float4*>(&xs[c * 32]);
            #pragma unroll 2
            for (int g = 0; g < 4; ++g) {
                float2 P0 = srow[(g * 8 + 0) * HN];
                float2 P1 = srow[(g * 8 + 1) * HN];
                float2 P2 = srow[(g * 8 + 2) * HN];
                float2 P3 = srow[(g * 8 + 3) * HN];
                float2 P4 = srow[(g * 8 + 4) * HN];
                float2 P5 = srow[(g * 8 + 5) * HN];
                float2 P6 = srow[(g * 8 + 6) * HN];
                float2 P7 = srow[(g * 8 + 7) * HN];
                float4 va = xv4[2 * g], vb = xv4[2 * g + 1];
                sig_acc(P0, va.x, sn, sd);
                sig_acc(P1, va.y, sn, sd);
                sig_acc(P2, va.z, sn, sd);
                sig_acc(P3, va.w, sn, sd);
                sig_acc(P4, vb.x, sn, sd);
                sig_acc(P5, vb.y, sn, sd);
                sig_acc(P6, vb.z, sn, sd);
                sig_acc(P7, vb.w, sn, sd);
            }
            sredS[c][h][0] = sn;
            sredS[c][h][1] = sd;
        }
        __syncthreads();
        if (tid < HN) {
            wns = sredS[0][tid][0] + sredS[1][tid][0] + sredS[2][tid][0] + sredS[3][tid][0];
            wds = sredS[0][tid][1] + sredS[1][tid][1] + sredS[2][tid][1] + sredS[3][tid][1];
        }

        // ---- 6 ODE unfolds: 64 elements per thread ----
        #pragma unroll 1
        for (int k = 0; k < NUNF; ++k) {
            float nm = 0.f, dn = 0.f;
            const float4* v4 = reinterpret_cast<const float4*>(&v_[c * 64]);
            #pragma unroll 2
            for (int g = 0; g < 8; ++g) {
                float2 P0 = prow[(g * 8 + 0) * HN];
                float2 P1 = prow[(g * 8 + 1) * HN];
                float2 P2 = prow[(g * 8 + 2) * HN];
                float2 P3 = prow[(g * 8 + 3) * HN];
                float2 P4 = prow[(g * 8 + 4) * HN];
                float2 P5 = prow[(g * 8 + 5) * HN];
                float2 P6 = prow[(g * 8 + 6) * HN];
                float2 P7 = prow[(g * 8 + 7) * HN];
                float4 va = v4[2 * g], vb = v4[2 * g + 1];
                sig_acc(P0, va.x, nm, dn);
                sig_acc(P1, va.y, nm, dn);
                sig_acc(P2, va.z, nm, dn);
                sig_acc(P3, va.w, nm, dn);
                sig_acc(P4, vb.x, nm, dn);
                sig_acc(P5, vb.y, nm, dn);
                sig_acc(P6, vb.z, nm, dn);
                sig_acc(P7, vb.w, nm, dn);
            }
            sred[c][h][0] = nm;
            sred[c][h][1] = dn;
            __syncthreads();
            if (tid < HN) {
                float num = sred[0][tid][0] + sred[1][tid][0] + sred[2][tid][0] + sred[3][tid][0] + wns;
                float den = sred[0][tid][1] + sred[1][tid][1] + sred[2][tid][1] + sred[3][tid][1] + wds;
                float vo = v_[tid];
                num = fmaf(cmt, vo, gv) + num;
                den = dcn + den + 1e-8f;
                vnew = num * frcp(den);
                v_[tid] = vnew;
            }
            __syncthreads();
        }

        if (tid < HN) orow[(size_t)t * HN + tid] = vnew;
    }
    if (tid < HN) out[(size_t)BN * SL * HN + (size_t)b * HN + tid] = vnew;
}

extern "C" void kernel_launch(void* const* d_in, const int* in_sizes, int n_in,
                              void* d_out, int out_size, void* d_ws, size_t ws_size,
                              hipStream_t stream) {
    const float* x     = (const float*)d_in[0];
    const float* gleak = (const float*)d_in[1];
    const float* vleak = (const float*)d_in[2];
    const float* cm    = (const float*)d_in[3];
    const float* w     = (const float*)d_in[4];
    const float* sigma = (const float*)d_in[5];
    const float* mu    = (const float*)d_in[6];
    const float* erev  = (const float*)d_in[7];
    const float* sw    = (const float*)d_in[8];
    const float* ssig  = (const float*)d_in[9];
    const float* smu   = (const float*)d_in[10];
    const float* serev = (const float*)d_in[11];
    const float* iw    = (const float*)d_in[12];
    const float* ib    = (const float*)d_in[13];

    float* ws = (float*)d_ws;

    ltc_prep<<<128, 256, 0, stream>>>(gleak, vleak, cm, w, sigma, mu, erev,
                                      sw, ssig, smu, serev, iw, ib, ws);

    const float2* rp2  = (const float2*)ws;
    const float2* spp2 = (const float2*)ws + HN * HN;
    const float*  hv   = ws + 2 * (HN * HN + DN * HN);
    ltc_main<<<BN, 1024, 0, stream>>>(x, rp2, spp2, hv, (float*)d_out);
}